// Round 2
// baseline (794.137 us; speedup 1.0000x reference)
//
#include <hip/hip_runtime.h>

#define BATCH 16384
#define N_NEG 10
#define N_DIM 128
#define EPW 4   // batch elements per wave

__device__ __forceinline__ float log_sigmoid(float x) {
    // stable: min(x,0) - log1p(exp(-|x|))
    return fminf(x, 0.0f) - log1pf(__expf(-fabsf(x)));
}

// 4 batch elements per 64-lane wave.
// - Element ids are wave-uniform -> all 52 embedding-row indices come via
//   s_load and all row base addresses are SGPR pairs.
// - All 52 row loads (global_load_dwordx2, 64 lanes * 8 B = one 512 B row per
//   instruction) are issued before any reduction: 52 rows in flight per wave.
//   At ~135 VGPR -> 3 waves/SIMD -> ~156 rows in flight per SIMD (1.5x the
//   previous 104, which was invariant across v0/v1 and explains their tie).
// - acc[12] is recycled per element: reduce+store element e while elements
//   e+1.. are still in flight.
__global__ __launch_bounds__(256) void all2vec_kernel(
    const int*   __restrict__ pos_v,
    const int*   __restrict__ pos_u,
    const int*   __restrict__ neg,
    const float* __restrict__ weights,
    const float* __restrict__ emb,
    const float* __restrict__ emb_ctx,
    float*       __restrict__ out)
{
    const int lane = threadIdx.x & 63;
    const int waveInBlock = threadIdx.x >> 6;              // 4 waves / block
    const int w  = __builtin_amdgcn_readfirstlane(blockIdx.x * 4 + waveInBlock);
    const int b0 = w * EPW;

    const float2* e2 = (const float2*)emb;      // 64 float2 per 128-f row
    const float2* c2 = (const float2*)emb_ctx;

    // wave-uniform index loads -> scalar pipe
    int iv[EPW], iu[EPW];
    int nidx[EPW][N_NEG];
#pragma unroll
    for (int e = 0; e < EPW; ++e) {
        iv[e] = pos_v[b0 + e];
        iu[e] = pos_u[b0 + e];
#pragma unroll
        for (int k = 0; k < N_NEG; ++k)
            nidx[e][k] = neg[(b0 + e) * N_NEG + k];
    }

    // issue all 52 row loads back-to-back (independent -> max MLP)
    float2 v[EPW], ru[EPW], rc[EPW], rn[EPW][N_NEG];
#pragma unroll
    for (int e = 0; e < EPW; ++e) {
        v[e]  = e2[(long long)iv[e] * 64 + lane];
        ru[e] = e2[(long long)iu[e] * 64 + lane];
        rc[e] = c2[(long long)iu[e] * 64 + lane];
#pragma unroll
        for (int k = 0; k < N_NEG; ++k)
            rn[e][k] = c2[(long long)nidx[e][k] * 64 + lane];
    }

    // per element: fma -> full-wave butterfly -> store; acc regs recycle
#pragma unroll
    for (int e = 0; e < EPW; ++e) {
        float acc[12];
        acc[0] = ru[e].x * v[e].x + ru[e].y * v[e].y;
        acc[1] = rc[e].x * v[e].x + rc[e].y * v[e].y;
#pragma unroll
        for (int k = 0; k < N_NEG; ++k)
            acc[2 + k] = rn[e][k].x * v[e].x + rn[e][k].y * v[e].y;

#pragma unroll
        for (int j = 0; j < 12; ++j) {
#pragma unroll
            for (int m = 32; m > 0; m >>= 1)
                acc[j] += __shfl_xor(acc[j], m, 64);
        }

        if (lane == 0) {
            const float wt = weights[b0 + e];
            float negsum = 0.0f;
#pragma unroll
            for (int k = 0; k < N_NEG; ++k)
                negsum += log_sigmoid(-acc[2 + k]);
            out[b0 + e]         = wt * (-log_sigmoid(acc[0]) - negsum);  // score_1
            out[BATCH + b0 + e] = wt * (-log_sigmoid(acc[1]) - negsum); // score_2
        }
    }
}

extern "C" void kernel_launch(void* const* d_in, const int* in_sizes, int n_in,
                              void* d_out, int out_size, void* d_ws, size_t ws_size,
                              hipStream_t stream) {
    const int*   pos_v   = (const int*)d_in[0];
    const int*   pos_u   = (const int*)d_in[1];
    const int*   neg     = (const int*)d_in[2];
    const float* weights = (const float*)d_in[3];
    const float* emb     = (const float*)d_in[4];
    const float* emb_ctx = (const float*)d_in[5];
    float*       out     = (float*)d_out;

    const int waves_total = BATCH / EPW;      // 4096 waves
    const int blocks = waves_total / 4;       // 4 waves (256 thr) per block -> 1024
    all2vec_kernel<<<blocks, 256, 0, stream>>>(pos_v, pos_u, neg, weights,
                                               emb, emb_ctx, out);
}